// Round 17
// baseline (2033.279 us; speedup 1.0000x reference)
//
#include <hip/hip_runtime.h>
#include <cstdint>

// R17: final consolidation vs R16 (1905us). GEMM + all compute bodies FROZEN.
// 1) ln_both: mol+prot LN one dispatch (320thr; mol predicated tid<128, barriers
//    unconditional -- no wave-exit hazard).
// 2) pool(slot l) folded into agg dispatch of iter l (same x state; disjoint
//    outputs). Slot-0/slot-4 pools standalone. Per-layer 6 -> 4 dispatches.

constexpr int H_HEADS = 3;
constexpr float NEG_SLOPE = 0.2f;
constexpr float LN_EPS = 1e-5f;
constexpr int N_MOL = 40000, E_MOL = 80000, C_MOL = 512, G_MOL = 512;
constexpr int N_PROT = 8000, E_PROT = 64000, C_PROT = 1280, G_PROT = 32;
constexpr int LAYERS = 4;
constexpr int MPAD_MOL = 40064;
constexpr int MPAD_PROT = 8064;
constexpr int VOCAB = 512 * 9 + 1;
constexpr int FOLD_F32 = LAYERS * H_HEADS * (C_MOL + C_MOL + C_PROT + C_PROT);  // 43008
constexpr int POOLB_MOL = G_MOL * 8;    // 4096
constexpr int POOLB = POOLB_MOL + G_PROT * 64;  // 6144

typedef unsigned short u16;
typedef __attribute__((ext_vector_type(8))) short short8v;
typedef __attribute__((ext_vector_type(4))) unsigned short ushort4v;
typedef __attribute__((ext_vector_type(4))) float f32x4;

__device__ __forceinline__ float bf2f(u16 s) {
    union { unsigned u; float f; } v; v.u = ((unsigned)s) << 16; return v.f;
}
__device__ __forceinline__ u16 f2bf(float f) {
    union { float f; unsigned u; } v; v.f = f;
    return (u16)((v.u + 0x7fffu + ((v.u >> 16) & 1u)) >> 16);
}

__device__ __forceinline__ void g2l16(const void* g, void* l) {
    __builtin_amdgcn_global_load_lds((const __attribute__((address_space(1))) void*)g,
                                     (__attribute__((address_space(3))) void*)l, 16, 0, 0);
}

// ---------------- merged setup kernels ----------------

__global__ void init_all(int* cntM, int* cntP, int* gcntM, int* gcntP, float* folds,
                         float* out, int out_n) {
    const int i = blockIdx.x * blockDim.x + threadIdx.x;
    int r = i;
    if (r < N_MOL) { cntM[r] = 1; return; }
    r -= N_MOL;
    if (r < N_PROT) { cntP[r] = 1; return; }
    r -= N_PROT;
    if (r < G_MOL) { gcntM[r] = 0; return; }
    r -= G_MOL;
    if (r < G_PROT) { gcntP[r] = 0; return; }
    r -= G_PROT;
    if (r < FOLD_F32) { folds[r] = 0.f; return; }
    r -= FOLD_F32;
    if (r < out_n) out[r] = 0.f;
}

__global__ void hist_both(const int* __restrict__ dstM, int* cntM, const int* __restrict__ dstP,
                          int* cntP) {
    const int i = blockIdx.x * blockDim.x + threadIdx.x;
    if (i < E_MOL) atomicAdd(&cntM[dstM[i]], 1);
    else if (i < E_MOL + E_PROT) atomicAdd(&cntP[dstP[i - E_MOL]], 1);
}

__global__ void scan2(const int* __restrict__ in0, int* __restrict__ out0, int n0,
                      const int* __restrict__ in1, int* __restrict__ out1, int n1) {
    __shared__ int sums[1024];
    const int* in = blockIdx.x == 0 ? in0 : in1;
    int* out = blockIdx.x == 0 ? out0 : out1;
    const int n = blockIdx.x == 0 ? n0 : n1;
    const int t = threadIdx.x;
    const int chunk = (n + 1023) / 1024;
    const int start = t * chunk;
    const int end = min(start + chunk, n);
    int s = 0;
    for (int i = start; i < end; ++i) s += in[i];
    sums[t] = s;
    __syncthreads();
    if (t == 0) {
        int acc = 0;
        for (int i = 0; i < 1024; ++i) { int v = sums[i]; sums[i] = acc; acc += v; }
        out[n] = acc;
    }
    __syncthreads();
    int acc = sums[t];
    for (int i = start; i < end; ++i) { out[i] = acc; acc += in[i]; }
}

__global__ void copy_pos_both(const int* __restrict__ ipM, int* posM, const int* __restrict__ ipP,
                              int* posP) {
    const int i = blockIdx.x * blockDim.x + threadIdx.x;
    if (i < N_MOL) posM[i] = ipM[i];
    else if (i < N_MOL + N_PROT) posP[i - N_MOL] = ipP[i - N_MOL];
}

__global__ void fill_self_both(int* posM, int* srclM, int* posP, int* srclP) {
    const int i = blockIdx.x * blockDim.x + threadIdx.x;
    if (i < N_MOL) { int s = atomicAdd(&posM[i], 1); srclM[s] = i; }
    else if (i < N_MOL + N_PROT) {
        const int n = i - N_MOL;
        int s = atomicAdd(&posP[n], 1);
        srclP[s] = n;
    }
}

__global__ void fill_edge_both(const int* __restrict__ eiM, int* posM, int* srclM,
                               const int* __restrict__ eiP, int* posP, int* srclP) {
    const int i = blockIdx.x * blockDim.x + threadIdx.x;
    if (i < E_MOL) {
        int s = atomicAdd(&posM[eiM[E_MOL + i]], 1);
        srclM[s] = eiM[i];
    } else if (i < E_MOL + E_PROT) {
        const int e = i - E_MOL;
        int s = atomicAdd(&posP[eiP[E_PROT + e]], 1);
        srclP[s] = eiP[e];
    }
}

__global__ void hist_batch_both(const int* __restrict__ bM, int* gcntM, const int* __restrict__ bP,
                                int* gcntP) {
    const int i = blockIdx.x * blockDim.x + threadIdx.x;
    if (i < N_MOL) atomicAdd(&gcntM[bM[i]], 1);
    else if (i < N_MOL + N_PROT) atomicAdd(&gcntP[bP[i - N_MOL]], 1);
}

__global__ void f32bf_both(const float* __restrict__ a, u16* __restrict__ oa, int na,
                           const float* __restrict__ b, u16* __restrict__ ob, int nb) {
    const int i = blockIdx.x * blockDim.x + threadIdx.x;
    if (i < na) oa[i] = f2bf(a[i]);
    else if (i < na + nb) ob[i - na] = f2bf(b[i - na]);
}

// ---------------- embedding mean (bf16 table, vectorized) ----------------

__global__ __launch_bounds__(128) void embed_mean_v(const int* __restrict__ drug_x,
                                                    const u16* __restrict__ emb_bf,
                                                    u16* __restrict__ out) {
    const int n = blockIdx.x;
    __shared__ int idx[9];
    if (threadIdx.x < 9) idx[threadIdx.x] = drug_x[n * 9 + threadIdx.x];
    __syncthreads();
    const int c4 = threadIdx.x * 4;
    float a0 = 0.f, a1 = 0.f, a2 = 0.f, a3 = 0.f;
#pragma unroll
    for (int t = 0; t < 9; ++t) {
        const ushort4v v = *(const ushort4v*)(emb_bf + (size_t)idx[t] * C_MOL + c4);
        a0 += bf2f(v.x); a1 += bf2f(v.y); a2 += bf2f(v.z); a3 += bf2f(v.w);
    }
    ushort4v r;
    r.x = f2bf(a0 * (1.f / 9.f)); r.y = f2bf(a1 * (1.f / 9.f));
    r.z = f2bf(a2 * (1.f / 9.f)); r.w = f2bf(a3 * (1.f / 9.f));
    *(ushort4v*)(out + (size_t)n * C_MOL + c4) = r;
}

// ---------------- fused transpose + fold (both modalities) ----------------

__device__ __forceinline__ void tf_tile(const float* __restrict__ W, u16* __restrict__ Wt,
                                        const float* __restrict__ asrc,
                                        const float* __restrict__ adst, float* __restrict__ wsrc,
                                        float* __restrict__ wdst, int CIN, int COUT,
                                        size_t headStride, int ldn, int h, int n0, int k0) {
    __shared__ float t[32][33];
    __shared__ float rs[8][33], rd[8][33];
    const int tx = threadIdx.x & 31, ty = threadIdx.x >> 5;
#pragma unroll
    for (int q = 0; q < 4; ++q)
        t[ty + q * 8][tx] = W[(size_t)(k0 + ty + q * 8) * (H_HEADS * COUT) + h * COUT + n0 + tx];
    __syncthreads();
#pragma unroll
    for (int q = 0; q < 4; ++q)
        Wt[(size_t)h * headStride + (size_t)(n0 + ty + q * 8) * ldn + k0 + tx] =
            f2bf(t[tx][ty + q * 8]);
    float ps = 0.f, pd = 0.f;
    const float* as = asrc + h * COUT + n0;
    const float* ad = adst + h * COUT + n0;
#pragma unroll
    for (int q = 0; q < 4; ++q) {
        const float w = t[tx][ty + q * 8];
        ps += w * as[ty + q * 8];
        pd += w * ad[ty + q * 8];
    }
    rs[ty][tx] = ps;
    rd[ty][tx] = pd;
    __syncthreads();
    if (ty == 0) {
        float s = 0.f, d = 0.f;
#pragma unroll
        for (int j = 0; j < 8; ++j) { s += rs[j][tx]; d += rd[j][tx]; }
        atomicAdd(&wsrc[h * CIN + k0 + tx], s);
        atomicAdd(&wdst[h * CIN + k0 + tx], d);
    }
}

constexpr int TF_MOL_BLOCKS = (C_MOL / 32) * (C_MOL / 32) * H_HEADS;     // 768
constexpr int TF_PROT_BLOCKS = (C_PROT / 32) * (C_PROT / 32) * H_HEADS;  // 4800

__global__ __launch_bounds__(256) void transfold_both(
    const float* __restrict__ WM, u16* __restrict__ WtM, const float* __restrict__ asrcM,
    const float* __restrict__ adstM, float* __restrict__ wsrcM, float* __restrict__ wdstM,
    const float* __restrict__ WP, u16* __restrict__ WtP, const float* __restrict__ asrcP,
    const float* __restrict__ adstP, float* __restrict__ wsrcP, float* __restrict__ wdstP) {
    const int bid = blockIdx.x;
    if (bid < TF_MOL_BLOCKS) {
        constexpr int G = C_MOL / 32;
        const int h = bid / (G * G), r = bid % (G * G);
        tf_tile(WM, WtM, asrcM, adstM, wsrcM, wdstM, C_MOL, C_MOL, (size_t)C_MOL, 3 * C_MOL, h,
                (r % G) * 32, (r / G) * 32);
    } else {
        constexpr int G = C_PROT / 32;
        const int b2 = bid - TF_MOL_BLOCKS;
        const int h = b2 / (G * G), r = b2 % (G * G);
        tf_tile(WP, WtP, asrcP, adstP, wsrcP, wdstP, C_PROT, C_PROT, (size_t)C_PROT, 3 * C_PROT, h,
                (r % G) * 32, (r / G) * 32);
    }
}

// ---------------- attention logits (layer 0, both modalities) ----------------

template <int C>
__device__ __forceinline__ void logits_node(const u16* __restrict__ x,
                                            const float* __restrict__ wsrc,
                                            const float* __restrict__ wdst,
                                            float* __restrict__ als, float* __restrict__ ald,
                                            int n) {
    constexpr int PER = C / 64;
    const int lane = threadIdx.x;
    const u16* xr = x + (size_t)n * C + lane * PER;
    float xv[PER];
#pragma unroll
    for (int i = 0; i < PER; i += 4) {
        const ushort4v v = *(const ushort4v*)(xr + i);
        xv[i] = bf2f(v.x); xv[i + 1] = bf2f(v.y); xv[i + 2] = bf2f(v.z); xv[i + 3] = bf2f(v.w);
    }
    for (int h = 0; h < H_HEADS; ++h) {
        const float* ws = wsrc + h * C + lane * PER;
        const float* wd = wdst + h * C + lane * PER;
        float ss = 0.f, sd = 0.f;
#pragma unroll
        for (int i = 0; i < PER; i += 4) {
            const float4 a = *(const float4*)(ws + i);
            const float4 b = *(const float4*)(wd + i);
            ss += xv[i] * a.x + xv[i + 1] * a.y + xv[i + 2] * a.z + xv[i + 3] * a.w;
            sd += xv[i] * b.x + xv[i + 1] * b.y + xv[i + 2] * b.z + xv[i + 3] * b.w;
        }
        for (int o = 32; o; o >>= 1) { ss += __shfl_down(ss, o); sd += __shfl_down(sd, o); }
        if (lane == 0) { als[n * H_HEADS + h] = ss; ald[n * H_HEADS + h] = sd; }
    }
}

__global__ __launch_bounds__(64) void logits_both(
    const u16* __restrict__ xM, const float* __restrict__ wsM, const float* __restrict__ wdM,
    float* __restrict__ alsM, float* __restrict__ aldM, const u16* __restrict__ xP,
    const float* __restrict__ wsP, const float* __restrict__ wdP, float* __restrict__ alsP,
    float* __restrict__ aldP) {
    const int b = blockIdx.x;
    if (b < N_MOL)
        logits_node<C_MOL>(xM, wsM, wdM, alsM, aldM, b);
    else
        logits_node<C_PROT>(xP, wsP, wdP, alsP, aldP, b - N_MOL);
}

// ---------------- pool bodies (shared by pool_both and agg_pool_both) ----------------

__device__ __forceinline__ void pool_block(const u16* __restrict__ xM,
                                           const int* __restrict__ goffM, float* __restrict__ outM,
                                           const u16* __restrict__ xP,
                                           const int* __restrict__ goffP, float* __restrict__ outP,
                                           int layer, int b) {
    const int tid = threadIdx.x;
    if (b < POOLB_MOL) {
        if (tid >= C_MOL / 4) return;
        const int g = b >> 3, seg = b & 7;
        const int beg = goffM[g], end = goffM[g + 1];
        const int len = end - beg;
        const int s0 = beg + (len * seg) / 8;
        const int s1 = beg + (len * (seg + 1)) / 8;
        if (s0 >= s1) return;
        const float inv = 1.f / fmaxf((float)len, 1.f);
        float a0 = 0.f, a1 = 0.f, a2 = 0.f, a3 = 0.f;
        for (int n = s0; n < s1; ++n) {
            const ushort4v v = *(const ushort4v*)(xM + (size_t)n * C_MOL + tid * 4);
            a0 += bf2f(v.x); a1 += bf2f(v.y); a2 += bf2f(v.z); a3 += bf2f(v.w);
        }
        float* o = outM + ((size_t)g * (LAYERS + 1) + layer) * C_MOL + tid * 4;
        atomicAdd(o + 0, a0 * inv);
        atomicAdd(o + 1, a1 * inv);
        atomicAdd(o + 2, a2 * inv);
        atomicAdd(o + 3, a3 * inv);
    } else {
        const int bb = b - POOLB_MOL;
        const int g = bb >> 6, seg = bb & 63;
        const int beg = goffP[g], end = goffP[g + 1];
        const int len = end - beg;
        const int s0 = beg + (len * seg) / 64;
        const int s1 = beg + (len * (seg + 1)) / 64;
        if (s0 >= s1) return;
        const float inv = 1.f / fmaxf((float)len, 1.f);
        float a0 = 0.f, a1 = 0.f, a2 = 0.f, a3 = 0.f;
        for (int n = s0; n < s1; ++n) {
            const ushort4v v = *(const ushort4v*)(xP + (size_t)n * C_PROT + tid * 4);
            a0 += bf2f(v.x); a1 += bf2f(v.y); a2 += bf2f(v.z); a3 += bf2f(v.w);
        }
        float* o = outP + ((size_t)g * (LAYERS + 1) + layer) * C_PROT + tid * 4;
        atomicAdd(o + 0, a0 * inv);
        atomicAdd(o + 1, a1 * inv);
        atomicAdd(o + 2, a2 * inv);
        atomicAdd(o + 3, a3 * inv);
    }
}

__global__ __launch_bounds__(320) void pool_both(const u16* __restrict__ xM,
                                                 const int* __restrict__ goffM,
                                                 float* __restrict__ outM,
                                                 const u16* __restrict__ xP,
                                                 const int* __restrict__ goffP,
                                                 float* __restrict__ outP, int layer) {
    pool_block(xM, goffM, outM, xP, goffP, outP, layer, blockIdx.x);
}

// ---------------- merged aggregates (+ optional appended pool blocks) ----------------

__device__ __forceinline__ void agg_mol_part(const u16* __restrict__ x,
                                             const float* __restrict__ als,
                                             const float* __restrict__ ald,
                                             const int* __restrict__ indptr,
                                             const int* __restrict__ srcl, u16* __restrict__ agg,
                                             float* smem) {
    constexpr int MAXD = 128;
    const int wv = threadIdx.x >> 6, lane = threadIdx.x & 63;
    const int n = blockIdx.x * 5 + wv;
    const int beg = indptr[n], end = indptr[n + 1];
    const int deg = end - beg;
    float* atab = smem + wv * (MAXD * 3);
    const float ad0 = ald[n * H_HEADS + 0], ad1 = ald[n * H_HEADS + 1], ad2 = ald[n * H_HEADS + 2];
    const bool fits = deg <= MAXD;
    if (fits) {
        for (int i = lane; i < deg * 3; i += 64) {
            const int e = i / 3, h = i - e * 3;
            float v = als[srcl[beg + e] * H_HEADS + h] + (h == 0 ? ad0 : (h == 1 ? ad1 : ad2));
            atab[i] = v >= 0.f ? v : NEG_SLOPE * v;
        }
    }
    __syncthreads();
    float m = -1e30f, zi = 0.f;
    if (lane < H_HEADS) {
        if (fits) {
            for (int e = 0; e < deg; ++e) m = fmaxf(m, atab[e * 3 + lane]);
            float z = 0.f;
            for (int e = 0; e < deg; ++e) z += __expf(atab[e * 3 + lane] - m);
            zi = 1.f / (z + 1e-16f);
        } else {
            const float ad = lane == 0 ? ad0 : (lane == 1 ? ad1 : ad2);
            for (int e = beg; e < end; ++e) {
                float v = als[srcl[e] * H_HEADS + lane] + ad;
                v = v >= 0.f ? v : NEG_SLOPE * v;
                m = fmaxf(m, v);
            }
            float z = 0.f;
            for (int e = beg; e < end; ++e) {
                float v = als[srcl[e] * H_HEADS + lane] + ad;
                v = v >= 0.f ? v : NEG_SLOPE * v;
                z += __expf(v - m);
            }
            zi = 1.f / (z + 1e-16f);
        }
    }
    const float m0 = __shfl(m, 0), m1 = __shfl(m, 1), m2 = __shfl(m, 2);
    const float z0 = __shfl(zi, 0), z1 = __shfl(zi, 1), z2 = __shfl(zi, 2);
    if (fits) {
        for (int i = lane; i < deg * 3; i += 64) {
            const int h = i - (i / 3) * 3;
            atab[i] = __expf(atab[i] - (h == 0 ? m0 : (h == 1 ? m1 : m2))) *
                      (h == 0 ? z0 : (h == 1 ? z1 : z2));
        }
    }
    __syncthreads();
    float acc[H_HEADS][8];
#pragma unroll
    for (int h = 0; h < H_HEADS; ++h)
#pragma unroll
        for (int j = 0; j < 8; ++j) acc[h][j] = 0.f;
    for (int e = 0; e < deg; ++e) {
        const int s = srcl[beg + e];
        float a0, a1, a2;
        if (fits) {
            a0 = atab[e * 3 + 0]; a1 = atab[e * 3 + 1]; a2 = atab[e * 3 + 2];
        } else {
            float v0 = als[s * H_HEADS + 0] + ad0; v0 = v0 >= 0.f ? v0 : NEG_SLOPE * v0;
            float v1 = als[s * H_HEADS + 1] + ad1; v1 = v1 >= 0.f ? v1 : NEG_SLOPE * v1;
            float v2 = als[s * H_HEADS + 2] + ad2; v2 = v2 >= 0.f ? v2 : NEG_SLOPE * v2;
            a0 = __expf(v0 - m0) * z0; a1 = __expf(v1 - m1) * z1; a2 = __expf(v2 - m2) * z2;
        }
        const short8v row = *(const short8v*)(x + (size_t)s * C_MOL + lane * 8);
#pragma unroll
        for (int j = 0; j < 8; ++j) {
            const float f = bf2f((u16)row[j]);
            acc[0][j] += a0 * f; acc[1][j] += a1 * f; acc[2][j] += a2 * f;
        }
    }
    u16* o = agg + (size_t)n * (3 * C_MOL) + lane * 8;
#pragma unroll
    for (int h = 0; h < H_HEADS; ++h) {
        short8v r;
#pragma unroll
        for (int j = 0; j < 8; ++j) r[j] = (short)f2bf(acc[h][j]);
        *(short8v*)(o + h * C_MOL) = r;
    }
}

__device__ __forceinline__ void agg_prot_part(const u16* __restrict__ x,
                                              const float* __restrict__ als,
                                              const float* __restrict__ ald,
                                              const int* __restrict__ indptr,
                                              const int* __restrict__ srcl, u16* __restrict__ agg,
                                              float* smem, int n) {
    constexpr int MAXD = 500;
    const int tid = threadIdx.x;
    const int beg = indptr[n], end = indptr[n + 1];
    const int deg = end - beg;
    float* mz = smem;
    float* atab = smem + 6;
    const float ad0 = ald[n * H_HEADS + 0], ad1 = ald[n * H_HEADS + 1], ad2 = ald[n * H_HEADS + 2];
    const bool fits = deg <= MAXD;
    if (fits) {
        for (int i = tid; i < deg * 3; i += 320) {
            const int e = i / 3, h = i - e * 3;
            float v = als[srcl[beg + e] * H_HEADS + h] + (h == 0 ? ad0 : (h == 1 ? ad1 : ad2));
            atab[i] = v >= 0.f ? v : NEG_SLOPE * v;
        }
    }
    __syncthreads();
    if (tid < H_HEADS) {
        float m = -1e30f, z = 0.f;
        if (fits) {
            for (int e = 0; e < deg; ++e) m = fmaxf(m, atab[e * 3 + tid]);
            for (int e = 0; e < deg; ++e) z += __expf(atab[e * 3 + tid] - m);
        } else {
            const float ad = tid == 0 ? ad0 : (tid == 1 ? ad1 : ad2);
            for (int e = beg; e < end; ++e) {
                float v = als[srcl[e] * H_HEADS + tid] + ad;
                v = v >= 0.f ? v : NEG_SLOPE * v;
                m = fmaxf(m, v);
            }
            for (int e = beg; e < end; ++e) {
                float v = als[srcl[e] * H_HEADS + tid] + ad;
                v = v >= 0.f ? v : NEG_SLOPE * v;
                z += __expf(v - m);
            }
        }
        mz[tid] = m;
        mz[3 + tid] = 1.f / (z + 1e-16f);
    }
    __syncthreads();
    const float m0 = mz[0], m1 = mz[1], m2 = mz[2];
    const float z0 = mz[3], z1 = mz[4], z2 = mz[5];
    if (fits) {
        for (int i = tid; i < deg * 3; i += 320) {
            const int h = i - (i / 3) * 3;
            atab[i] = __expf(atab[i] - (h == 0 ? m0 : (h == 1 ? m1 : m2))) *
                      (h == 0 ? z0 : (h == 1 ? z1 : z2));
        }
    }
    __syncthreads();
    float acc[H_HEADS][4];
#pragma unroll
    for (int h = 0; h < H_HEADS; ++h)
#pragma unroll
        for (int j = 0; j < 4; ++j) acc[h][j] = 0.f;
    for (int e = 0; e < deg; ++e) {
        const int s = srcl[beg + e];
        float a0, a1, a2;
        if (fits) {
            a0 = atab[e * 3 + 0]; a1 = atab[e * 3 + 1]; a2 = atab[e * 3 + 2];
        } else {
            float v0 = als[s * H_HEADS + 0] + ad0; v0 = v0 >= 0.f ? v0 : NEG_SLOPE * v0;
            float v1 = als[s * H_HEADS + 1] + ad1; v1 = v1 >= 0.f ? v1 : NEG_SLOPE * v1;
            float v2 = als[s * H_HEADS + 2] + ad2; v2 = v2 >= 0.f ? v2 : NEG_SLOPE * v2;
            a0 = __expf(v0 - m0) * z0; a1 = __expf(v1 - m1) * z1; a2 = __expf(v2 - m2) * z2;
        }
        const ushort4v v = *(const ushort4v*)(x + (size_t)s * C_PROT + tid * 4);
        const float f0 = bf2f(v.x), f1 = bf2f(v.y), f2 = bf2f(v.z), f3 = bf2f(v.w);
        acc[0][0] += a0 * f0; acc[0][1] += a0 * f1; acc[0][2] += a0 * f2; acc[0][3] += a0 * f3;
        acc[1][0] += a1 * f0; acc[1][1] += a1 * f1; acc[1][2] += a1 * f2; acc[1][3] += a1 * f3;
        acc[2][0] += a2 * f0; acc[2][1] += a2 * f1; acc[2][2] += a2 * f2; acc[2][3] += a2 * f3;
    }
    u16* o = agg + (size_t)n * (3 * C_PROT) + tid * 4;
#pragma unroll
    for (int h = 0; h < H_HEADS; ++h) {
        ushort4v r;
        r.x = f2bf(acc[h][0]); r.y = f2bf(acc[h][1]); r.z = f2bf(acc[h][2]); r.w = f2bf(acc[h][3]);
        *(ushort4v*)(o + h * C_PROT) = r;
    }
}

__global__ __launch_bounds__(320) void agg_pool_both(
    const u16* __restrict__ xM, const float* __restrict__ alsM, const float* __restrict__ aldM,
    const int* __restrict__ iptrM, const int* __restrict__ srclM, u16* __restrict__ aggM,
    const u16* __restrict__ xP, const float* __restrict__ alsP, const float* __restrict__ aldP,
    const int* __restrict__ iptrP, const int* __restrict__ srclP, u16* __restrict__ aggP,
    int molBlocks, int aggBlocks, const int* __restrict__ goffM, float* __restrict__ outM,
    const int* __restrict__ goffP, float* __restrict__ outP, int layer) {
    __shared__ float smem[1920];
    const int b = blockIdx.x;
    if (b < molBlocks)
        agg_mol_part(xM, alsM, aldM, iptrM, srclM, aggM, smem);
    else if (b < aggBlocks)
        agg_prot_part(xP, alsP, aldP, iptrP, srclP, aggP, smem, b - molBlocks);
    else
        pool_block(xM, goffM, outM, xP, goffP, outP, layer, b - aggBlocks);
}

// ---------------- GEMM: 128x128 tile, BK=64, DBUF 64KB + counted vmcnt (R15 proven) ----------------

__global__ __launch_bounds__(256) void gemm128p(
    const u16* __restrict__ A0, const u16* __restrict__ B0, u16* __restrict__ C0,
    int N0, int K0, int nx0, int M0, int g0,
    const u16* __restrict__ A1, const u16* __restrict__ B1, u16* __restrict__ C1,
    int N1, int K1, int nx1, int M1) {
    __shared__ u16 lds[32768];
    const int tid = threadIdx.x;
    const int w = tid >> 6, l = tid & 63;
    const int wr = w >> 1, wc = w & 1;

    const int bid = blockIdx.x;
    const u16 *A, *Bt;
    u16* Cout;
    int N, K, nxch, Mreal, base, sz;
    if (bid < g0) { base = 0; sz = g0; A = A0; Bt = B0; Cout = C0; N = N0; K = K0; nxch = nx0; Mreal = M0; }
    else { base = g0; sz = gridDim.x - g0; A = A1; Bt = B1; Cout = C1; N = N1; K = K1; nxch = nx1; Mreal = M1; }
    const int j = bid - base;
    const int q = sz >> 3, r = sz & 7;
    const int xcd = j & 7, idx = j >> 3;
    const int wg = (xcd < r ? xcd * (q + 1) : r * (q + 1) + (xcd - r) * q) + idx;
    const int nx = wg % nxch, my = wg / nxch;
    const size_t bm = (size_t)my * 128, bn = (size_t)nx * 128;

    const f32x4 zf = {0.f, 0.f, 0.f, 0.f};
    f32x4 acc[4][4];
#pragma unroll
    for (int i = 0; i < 4; ++i)
#pragma unroll
        for (int jj = 0; jj < 4; ++jj) acc[i][jj] = zf;

    const int srow = w * 32 + (l >> 3);
    const int sseg = (l & 7) ^ (l >> 3);
    const u16* Ab = A + (bm + srow) * (size_t)K + sseg * 8;
    const u16* Bb = Bt + (bn + srow) * (size_t)K + sseg * 8;

    auto stage = [&](int buf, int k0) {
        u16* La = lds + buf * 16384;
#pragma unroll
        for (int qq = 0; qq < 4; ++qq)
            g2l16(Ab + k0 + (size_t)qq * 8 * K, La + (w * 4 + qq) * 512);
#pragma unroll
        for (int qq = 0; qq < 4; ++qq)
            g2l16(Bb + k0 + (size_t)qq * 8 * K, La + 8192 + (w * 4 + qq) * 512);
    };

    const int nt = K >> 6;
    stage(0, 0);
    for (int t = 0; t < nt; ++t) {
        const int cur = t & 1;
        if (t + 1 < nt) {
            stage(cur ^ 1, (t + 1) << 6);
            asm volatile("s_waitcnt vmcnt(8)" ::: "memory");
        } else {
            asm volatile("s_waitcnt vmcnt(0)" ::: "memory");
        }
        __builtin_amdgcn_s_barrier();
        __builtin_amdgcn_sched_barrier(0);
        const u16* Lb = lds + cur * 16384;
#pragma unroll
        for (int kk = 0; kk < 2; ++kk) {
            const int sg = ((kk * 4 + (l >> 4)) ^ (l & 7)) * 8;
            short8v af[4], bf8[4];
#pragma unroll
            for (int fm = 0; fm < 4; ++fm) {
                const int row = wr * 64 + fm * 16 + (l & 15);
                af[fm] = *(const short8v*)&Lb[row * 64 + sg];
            }
#pragma unroll
            for (int fn = 0; fn < 4; ++fn) {
                const int row = wc * 64 + fn * 16 + (l & 15);
                bf8[fn] = *(const short8v*)&Lb[8192 + row * 64 + sg];
            }
#pragma unroll
            for (int fm = 0; fm < 4; ++fm)
#pragma unroll
                for (int fn = 0; fn < 4; ++fn)
                    acc[fm][fn] = __builtin_amdgcn_mfma_f32_16x16x32_bf16(af[fm], bf8[fn],
                                                                          acc[fm][fn], 0, 0, 0);
        }
        __builtin_amdgcn_sched_barrier(0);
        __builtin_amdgcn_s_barrier();
    }

#pragma unroll
    for (int half = 0; half < 2; ++half) {
        if (wr == half) {
#pragma unroll
            for (int fm = 0; fm < 4; ++fm)
#pragma unroll
                for (int fn = 0; fn < 4; ++fn) {
                    const int col = wc * 64 + fn * 16 + (l & 15);
#pragma unroll
                    for (int rr = 0; rr < 4; ++rr)
                        lds[(fm * 16 + (l >> 4) * 4 + rr) * 136 + col] = f2bf(acc[fm][fn][rr]);
                }
        }
        __syncthreads();
        const int lrow = tid >> 2, lseg = tid & 3;
        const size_t grow = bm + half * 64 + lrow;
        if (grow < (size_t)Mreal) {
            u16* Crow = Cout + grow * (size_t)N + bn + lseg * 32;
            const u16* Lr = lds + lrow * 136 + lseg * 32;
#pragma unroll
            for (int ii = 0; ii < 4; ++ii)
                *(float4*)(Crow + ii * 8) = *(const float4*)(Lr + ii * 8);
        }
        __syncthreads();
    }
}

// ---------------- LN (both modalities, one dispatch); predicated, barriers unconditional ----------------

template <int C, int LOGITS>
__device__ __forceinline__ void ln_node(u16* __restrict__ x, const float* __restrict__ bias,
                                        const float* __restrict__ g, const float* __restrict__ b,
                                        const float* __restrict__ wsrc_n,
                                        const float* __restrict__ wdst_n, float* __restrict__ als,
                                        float* __restrict__ ald, int n, float* red, float* red2) {
    constexpr int NT = C / 4;       // 128 (mol) or 320 (prot)
    constexpr int NW = NT / 64;     // 2 or 5
    const int tid = threadIdx.x;
    const bool act = tid < NT;
    constexpr float invH = 1.f / (float)H_HEADS;
    u16* xr = x + (size_t)n * C + tid * 4;
    float v0 = 0.f, v1 = 0.f, v2 = 0.f, v3 = 0.f;
    if (act) {
        const ushort4v xv = *(const ushort4v*)xr;
        const float4 bi = *(const float4*)(bias + tid * 4);
        v0 = bf2f(xv.x) * invH + bi.x;
        v1 = bf2f(xv.y) * invH + bi.y;
        v2 = bf2f(xv.z) * invH + bi.z;
        v3 = bf2f(xv.w) * invH + bi.w;
    }
    float s1 = v0 + v1 + v2 + v3;
    float s2 = v0 * v0 + v1 * v1 + v2 * v2 + v3 * v3;
    for (int o = 32; o; o >>= 1) { s1 += __shfl_down(s1, o); s2 += __shfl_down(s2, o); }
    if (act && (tid & 63) == 0) { red[tid >> 6] = s1; red[8 + (tid >> 6)] = s2; }
    __syncthreads();
    float t1 = 0.f, t2 = 0.f;
#pragma unroll
    for (int i = 0; i < NW; ++i) { t1 += red[i]; t2 += red[8 + i]; }
    const float mu = t1 / C;
    const float var = t2 / C - mu * mu;
    const float rstd = rsqrtf(var + LN_EPS);
    float q0 = 0.f, q1 = 0.f, q2 = 0.f, q3 = 0.f;
    if (act) {
        const float4 gg = *(const float4*)(g + tid * 4);
        const float4 bb = *(const float4*)(b + tid * 4);
        ushort4v ov;
        ov.x = f2bf((v0 - mu) * rstd * gg.x + bb.x);
        ov.y = f2bf((v1 - mu) * rstd * gg.y + bb.y);
        ov.z = f2bf((v2 - mu) * rstd * gg.z + bb.z);
        ov.w = f2bf((v3 - mu) * rstd * gg.w + bb.w);
        *(ushort4v*)xr = ov;
        q0 = bf2f(ov.x); q1 = bf2f(ov.y); q2 = bf2f(ov.z); q3 = bf2f(ov.w);
    }
    if (LOGITS) {
        float ps[3] = {0.f, 0.f, 0.f}, pd[3] = {0.f, 0.f, 0.f};
        if (act) {
#pragma unroll
            for (int h = 0; h < 3; ++h) {
                const float4 a = *(const float4*)(wsrc_n + h * C + tid * 4);
                const float4 d = *(const float4*)(wdst_n + h * C + tid * 4);
                ps[h] = q0 * a.x + q1 * a.y + q2 * a.z + q3 * a.w;
                pd[h] = q0 * d.x + q1 * d.y + q2 * d.z + q3 * d.w;
            }
        }
        for (int o = 32; o; o >>= 1) {
#pragma unroll
            for (int h = 0; h < 3; ++h) {
                ps[h] += __shfl_down(ps[h], o);
                pd[h] += __shfl_down(pd[h], o);
            }
        }
        if (act && (tid & 63) == 0) {
            const int wv = tid >> 6;
#pragma unroll
            for (int h = 0; h < 3; ++h) { red2[wv * 6 + h] = ps[h]; red2[wv * 6 + 3 + h] = pd[h]; }
        }
        __syncthreads();
        if (tid == 0) {
#pragma unroll
            for (int h = 0; h < 3; ++h) {
                float as = 0.f, ad = 0.f;
#pragma unroll
                for (int i = 0; i < NW; ++i) { as += red2[i * 6 + h]; ad += red2[i * 6 + 3 + h]; }
                als[n * H_HEADS + h] = as;
                ald[n * H_HEADS + h] = ad;
            }
        }
    }
}

template <int LOGITS>
__global__ __launch_bounds__(320) void ln_both(
    u16* __restrict__ xM, const float* __restrict__ biasM, const float* __restrict__ gM,
    const float* __restrict__ bM, const float* __restrict__ wsM, const float* __restrict__ wdM,
    float* __restrict__ alsM, float* __restrict__ aldM, u16* __restrict__ xP,
    const float* __restrict__ biasP, const float* __restrict__ gP, const float* __restrict__ bP,
    const float* __restrict__ wsP, const float* __restrict__ wdP, float* __restrict__ alsP,
    float* __restrict__ aldP) {
    __shared__ float red[16];
    __shared__ float red2[32];
    const int b = blockIdx.x;
    if (b < N_MOL)
        ln_node<C_MOL, LOGITS>(xM, biasM, gM, bM, wsM, wdM, alsM, aldM, b, red, red2);
    else
        ln_node<C_PROT, LOGITS>(xP, biasP, gP, bP, wsP, wdP, alsP, aldP, b - N_MOL, red, red2);
}

// ---------------- launch ----------------

extern "C" void kernel_launch(void* const* d_in, const int* in_sizes, int n_in, void* d_out,
                              int out_size, void* d_ws, size_t ws_size, hipStream_t stream) {
    const int* drug_x      = (const int*)d_in[0];
    const int* mol_ei      = (const int*)d_in[1];
    const int* mol_batch   = (const int*)d_in[2];
    const float* prot_in   = (const float*)d_in[3];
    const int* prot_ei     = (const int*)d_in[4];
    const int* prot_batch  = (const int*)d_in[5];
    const float* emb       = (const float*)d_in[6];
    const float* mol_W     = (const float*)d_in[7];
    const float* mol_asrc  = (const float*)d_in[8];
    const float* mol_adst  = (const float*)d_in[9];
    const float* mol_bias  = (const float*)d_in[10];
    const float* mol_lng   = (const float*)d_in[11];
    const float* mol_lnb   = (const float*)d_in[12];
    const float* prot_W    = (const float*)d_in[13];
    const float* prot_asrc = (const float*)d_in[14];
    const float* prot_adst = (const float*)d_in[15];
    const float* prot_bias = (const float*)d_in[16];
    const float* prot_lng  = (const float*)d_in[17];
    const float* prot_lnb  = (const float*)d_in[18];

    if (ws_size < (size_t)262000000) return;

    char* base = (char*)d_ws;
    size_t off = 0;
    auto alloc = [&](size_t bytes) -> void* {
        void* r = base + off;
        off = (off + bytes + 255) & ~(size_t)255;
        return r;
    };
    u16* x_mol  = (u16*)alloc((size_t)N_MOL * C_MOL * 2);
    u16* x_prot = (u16*)alloc((size_t)N_PROT * C_PROT * 2);
    u16* aggM   = (u16*)alloc((size_t)3 * MPAD_MOL * C_MOL * 2);
    u16* WtM    = (u16*)alloc((size_t)H_HEADS * C_MOL * C_MOL * 2);
    u16* WtP    = (u16*)alloc((size_t)H_HEADS * C_PROT * C_PROT * 2);
    u16* aggP   = (u16*)alloc((size_t)3 * MPAD_PROT * C_PROT * 2);
    float* wsrcM = (float*)alloc((size_t)LAYERS * H_HEADS * C_MOL * 4);
    float* wdstM = (float*)alloc((size_t)LAYERS * H_HEADS * C_MOL * 4);
    float* wsrcP = (float*)alloc((size_t)LAYERS * H_HEADS * C_PROT * 4);
    float* wdstP = (float*)alloc((size_t)LAYERS * H_HEADS * C_PROT * 4);
    float* alsM = (float*)alloc((size_t)N_MOL * H_HEADS * 4);
    float* aldM = (float*)alloc((size_t)N_MOL * H_HEADS * 4);
    float* alsP = (float*)alloc((size_t)N_PROT * H_HEADS * 4);
    float* aldP = (float*)alloc((size_t)N_PROT * H_HEADS * 4);
    int* mol_indptr  = (int*)alloc((N_MOL + 1) * 4);
    int* mol_pos     = (int*)alloc(N_MOL * 4);
    int* mol_srcl    = (int*)alloc((E_MOL + N_MOL) * 4);
    int* prot_indptr = (int*)alloc((N_PROT + 1) * 4);
    int* prot_pos    = (int*)alloc(N_PROT * 4);
    int* prot_srcl   = (int*)alloc((E_PROT + N_PROT) * 4);
    int* cntM        = (int*)alloc(N_MOL * 4);
    int* cntP        = (int*)alloc(N_PROT * 4);
    int* mol_goff    = (int*)alloc((G_MOL + 1) * 4);
    int* prot_goff   = (int*)alloc((G_PROT + 1) * 4);
    int* gcntM       = (int*)alloc(G_MOL * 4);
    int* gcntP       = (int*)alloc(G_PROT * 4);

    u16* emb_bf = aggM;  // alias: aggM dead until first agg dispatch

    float* out_mol  = (float*)d_out;
    float* out_prot = (float*)d_out + (size_t)G_MOL * (LAYERS + 1) * C_MOL;

    {
        const int total = N_MOL + N_PROT + G_MOL + G_PROT + FOLD_F32 + out_size;
        init_all<<<(total + 255) / 256, 256, 0, stream>>>(cntM, cntP, gcntM, gcntP, wsrcM,
                                                          (float*)d_out, out_size);
    }

    hist_both<<<(E_MOL + E_PROT + 255) / 256, 256, 0, stream>>>(mol_ei + E_MOL, cntM,
                                                                prot_ei + E_PROT, cntP);
    scan2<<<2, 1024, 0, stream>>>(cntM, mol_indptr, N_MOL, cntP, prot_indptr, N_PROT);
    copy_pos_both<<<(N_MOL + N_PROT + 255) / 256, 256, 0, stream>>>(mol_indptr, mol_pos,
                                                                    prot_indptr, prot_pos);
    fill_self_both<<<(N_MOL + N_PROT + 255) / 256, 256, 0, stream>>>(mol_pos, mol_srcl, prot_pos,
                                                                     prot_srcl);
    fill_edge_both<<<(E_MOL + E_PROT + 255) / 256, 256, 0, stream>>>(mol_ei, mol_pos, mol_srcl,
                                                                     prot_ei, prot_pos, prot_srcl);
    hist_batch_both<<<(N_MOL + N_PROT + 255) / 256, 256, 0, stream>>>(mol_batch, gcntM, prot_batch,
                                                                      gcntP);
    scan2<<<2, 1024, 0, stream>>>(gcntM, mol_goff, G_MOL, gcntP, prot_goff, G_PROT);

    transfold_both<<<TF_MOL_BLOCKS + TF_PROT_BLOCKS, 256, 0, stream>>>(
        mol_W, WtM, mol_asrc, mol_adst, wsrcM, wdstM,
        prot_W, WtP, prot_asrc, prot_adst, wsrcP, wdstP);

    f32bf_both<<<(VOCAB * C_MOL + N_PROT * C_PROT + 255) / 256, 256, 0, stream>>>(
        emb, emb_bf, VOCAB * C_MOL, prot_in, x_prot, N_PROT * C_PROT);
    embed_mean_v<<<N_MOL, 128, 0, stream>>>(drug_x, emb_bf, x_mol);
    pool_both<<<POOLB, 320, 0, stream>>>(x_mol, mol_goff, out_mol, x_prot, prot_goff, out_prot, 0);
    logits_both<<<N_MOL + N_PROT, 64, 0, stream>>>(x_mol, wsrcM, wdstM, alsM, aldM, x_prot, wsrcP,
                                                   wdstP, alsP, aldP);

    const int gMol = (MPAD_MOL / 128) * (C_MOL / 128);    // 1252
    const int gProt = (MPAD_PROT / 128) * (C_PROT / 128); // 630
    const int molAggBlocks = N_MOL / 5;                   // 8000
    const int aggBlocks = molAggBlocks + N_PROT;          // 16000

    for (int l = 0; l < LAYERS; ++l) {
        const int last = (l == LAYERS - 1);
        // agg (+ pool of slot l for l>=1: pools the same x state agg reads)
        agg_pool_both<<<aggBlocks + (l > 0 ? POOLB : 0), 320, 0, stream>>>(
            x_mol, alsM, aldM, mol_indptr, mol_srcl, aggM,
            x_prot, alsP, aldP, prot_indptr, prot_srcl, aggP,
            molAggBlocks, aggBlocks, mol_goff, out_mol, prot_goff, out_prot, l);
        gemm128p<<<gProt + gMol, 256, 0, stream>>>(
            aggP, WtP, x_prot, C_PROT, 3 * C_PROT, C_PROT / 128, N_PROT, gProt,
            aggM, WtM, x_mol, C_MOL, 3 * C_MOL, C_MOL / 128, N_MOL);
        if (!last) {
            transfold_both<<<TF_MOL_BLOCKS + TF_PROT_BLOCKS, 256, 0, stream>>>(
                mol_W + (size_t)(l + 1) * C_MOL * (H_HEADS * C_MOL), WtM,
                mol_asrc + (size_t)(l + 1) * H_HEADS * C_MOL,
                mol_adst + (size_t)(l + 1) * H_HEADS * C_MOL,
                wsrcM + (size_t)(l + 1) * H_HEADS * C_MOL,
                wdstM + (size_t)(l + 1) * H_HEADS * C_MOL,
                prot_W + (size_t)(l + 1) * C_PROT * (H_HEADS * C_PROT), WtP,
                prot_asrc + (size_t)(l + 1) * H_HEADS * C_PROT,
                prot_adst + (size_t)(l + 1) * H_HEADS * C_PROT,
                wsrcP + (size_t)(l + 1) * H_HEADS * C_PROT,
                wdstP + (size_t)(l + 1) * H_HEADS * C_PROT);
            ln_both<1><<<N_MOL + N_PROT, 320, 0, stream>>>(
                x_mol, mol_bias + (size_t)l * C_MOL, mol_lng + (size_t)l * C_MOL,
                mol_lnb + (size_t)l * C_MOL, wsrcM + (size_t)(l + 1) * H_HEADS * C_MOL,
                wdstM + (size_t)(l + 1) * H_HEADS * C_MOL, alsM, aldM,
                x_prot, prot_bias + (size_t)l * C_PROT, prot_lng + (size_t)l * C_PROT,
                prot_lnb + (size_t)l * C_PROT, wsrcP + (size_t)(l + 1) * H_HEADS * C_PROT,
                wdstP + (size_t)(l + 1) * H_HEADS * C_PROT, alsP, aldP);
        } else {
            ln_both<0><<<N_MOL + N_PROT, 320, 0, stream>>>(
                x_mol, mol_bias + (size_t)l * C_MOL, mol_lng + (size_t)l * C_MOL,
                mol_lnb + (size_t)l * C_MOL, nullptr, nullptr, alsM, aldM,
                x_prot, prot_bias + (size_t)l * C_PROT, prot_lng + (size_t)l * C_PROT,
                prot_lnb + (size_t)l * C_PROT, nullptr, nullptr, alsP, aldP);
        }
    }
    // final pool (slot LAYERS = 4) on the last LN output
    pool_both<<<POOLB, 320, 0, stream>>>(x_mol, mol_goff, out_mol, x_prot, prot_goff, out_prot,
                                         LAYERS);
}

// Round 18
// 1891.212 us; speedup vs baseline: 1.0751x; 1.0751x over previous
//
#include <hip/hip_runtime.h>
#include <cstdint>

// R18: exact revert to R16 (proven best, 1905us). R17's two merges both hurt:
// agg_pool_both extended the agg dispatch's critical path (172us top dispatch),
// ln_both wasted 60% of mol-LN wave slots (320thr, 128 active). R16 config:
// gemm128p (dbuf+vmcnt(8), 2blk/CU, 163us merged), agg_both, ln_kernel per
// modality, pool_both, consolidated setup.

constexpr int H_HEADS = 3;
constexpr float NEG_SLOPE = 0.2f;
constexpr float LN_EPS = 1e-5f;
constexpr int N_MOL = 40000, E_MOL = 80000, C_MOL = 512, G_MOL = 512;
constexpr int N_PROT = 8000, E_PROT = 64000, C_PROT = 1280, G_PROT = 32;
constexpr int LAYERS = 4;
constexpr int MPAD_MOL = 40064;
constexpr int MPAD_PROT = 8064;
constexpr int VOCAB = 512 * 9 + 1;
constexpr int FOLD_F32 = LAYERS * H_HEADS * (C_MOL + C_MOL + C_PROT + C_PROT);  // 43008

typedef unsigned short u16;
typedef __attribute__((ext_vector_type(8))) short short8v;
typedef __attribute__((ext_vector_type(4))) unsigned short ushort4v;
typedef __attribute__((ext_vector_type(4))) float f32x4;

__device__ __forceinline__ float bf2f(u16 s) {
    union { unsigned u; float f; } v; v.u = ((unsigned)s) << 16; return v.f;
}
__device__ __forceinline__ u16 f2bf(float f) {
    union { float f; unsigned u; } v; v.f = f;
    return (u16)((v.u + 0x7fffu + ((v.u >> 16) & 1u)) >> 16);
}

__device__ __forceinline__ void g2l16(const void* g, void* l) {
    __builtin_amdgcn_global_load_lds((const __attribute__((address_space(1))) void*)g,
                                     (__attribute__((address_space(3))) void*)l, 16, 0, 0);
}

// ---------------- merged setup kernels ----------------

__global__ void init_all(int* cntM, int* cntP, int* gcntM, int* gcntP, float* folds,
                         float* out, int out_n) {
    const int i = blockIdx.x * blockDim.x + threadIdx.x;
    int r = i;
    if (r < N_MOL) { cntM[r] = 1; return; }
    r -= N_MOL;
    if (r < N_PROT) { cntP[r] = 1; return; }
    r -= N_PROT;
    if (r < G_MOL) { gcntM[r] = 0; return; }
    r -= G_MOL;
    if (r < G_PROT) { gcntP[r] = 0; return; }
    r -= G_PROT;
    if (r < FOLD_F32) { folds[r] = 0.f; return; }
    r -= FOLD_F32;
    if (r < out_n) out[r] = 0.f;
}

__global__ void hist_both(const int* __restrict__ dstM, int* cntM, const int* __restrict__ dstP,
                          int* cntP) {
    const int i = blockIdx.x * blockDim.x + threadIdx.x;
    if (i < E_MOL) atomicAdd(&cntM[dstM[i]], 1);
    else if (i < E_MOL + E_PROT) atomicAdd(&cntP[dstP[i - E_MOL]], 1);
}

__global__ void scan2(const int* __restrict__ in0, int* __restrict__ out0, int n0,
                      const int* __restrict__ in1, int* __restrict__ out1, int n1) {
    __shared__ int sums[1024];
    const int* in = blockIdx.x == 0 ? in0 : in1;
    int* out = blockIdx.x == 0 ? out0 : out1;
    const int n = blockIdx.x == 0 ? n0 : n1;
    const int t = threadIdx.x;
    const int chunk = (n + 1023) / 1024;
    const int start = t * chunk;
    const int end = min(start + chunk, n);
    int s = 0;
    for (int i = start; i < end; ++i) s += in[i];
    sums[t] = s;
    __syncthreads();
    if (t == 0) {
        int acc = 0;
        for (int i = 0; i < 1024; ++i) { int v = sums[i]; sums[i] = acc; acc += v; }
        out[n] = acc;
    }
    __syncthreads();
    int acc = sums[t];
    for (int i = start; i < end; ++i) { out[i] = acc; acc += in[i]; }
}

__global__ void copy_pos_both(const int* __restrict__ ipM, int* posM, const int* __restrict__ ipP,
                              int* posP) {
    const int i = blockIdx.x * blockDim.x + threadIdx.x;
    if (i < N_MOL) posM[i] = ipM[i];
    else if (i < N_MOL + N_PROT) posP[i - N_MOL] = ipP[i - N_MOL];
}

__global__ void fill_self_both(int* posM, int* srclM, int* posP, int* srclP) {
    const int i = blockIdx.x * blockDim.x + threadIdx.x;
    if (i < N_MOL) { int s = atomicAdd(&posM[i], 1); srclM[s] = i; }
    else if (i < N_MOL + N_PROT) {
        const int n = i - N_MOL;
        int s = atomicAdd(&posP[n], 1);
        srclP[s] = n;
    }
}

__global__ void fill_edge_both(const int* __restrict__ eiM, int* posM, int* srclM,
                               const int* __restrict__ eiP, int* posP, int* srclP) {
    const int i = blockIdx.x * blockDim.x + threadIdx.x;
    if (i < E_MOL) {
        int s = atomicAdd(&posM[eiM[E_MOL + i]], 1);
        srclM[s] = eiM[i];
    } else if (i < E_MOL + E_PROT) {
        const int e = i - E_MOL;
        int s = atomicAdd(&posP[eiP[E_PROT + e]], 1);
        srclP[s] = eiP[e];
    }
}

__global__ void hist_batch_both(const int* __restrict__ bM, int* gcntM, const int* __restrict__ bP,
                                int* gcntP) {
    const int i = blockIdx.x * blockDim.x + threadIdx.x;
    if (i < N_MOL) atomicAdd(&gcntM[bM[i]], 1);
    else if (i < N_MOL + N_PROT) atomicAdd(&gcntP[bP[i - N_MOL]], 1);
}

__global__ void f32bf_both(const float* __restrict__ a, u16* __restrict__ oa, int na,
                           const float* __restrict__ b, u16* __restrict__ ob, int nb) {
    const int i = blockIdx.x * blockDim.x + threadIdx.x;
    if (i < na) oa[i] = f2bf(a[i]);
    else if (i < na + nb) ob[i - na] = f2bf(b[i - na]);
}

// ---------------- embedding mean (bf16 table, vectorized) ----------------

__global__ __launch_bounds__(128) void embed_mean_v(const int* __restrict__ drug_x,
                                                    const u16* __restrict__ emb_bf,
                                                    u16* __restrict__ out) {
    const int n = blockIdx.x;
    __shared__ int idx[9];
    if (threadIdx.x < 9) idx[threadIdx.x] = drug_x[n * 9 + threadIdx.x];
    __syncthreads();
    const int c4 = threadIdx.x * 4;
    float a0 = 0.f, a1 = 0.f, a2 = 0.f, a3 = 0.f;
#pragma unroll
    for (int t = 0; t < 9; ++t) {
        const ushort4v v = *(const ushort4v*)(emb_bf + (size_t)idx[t] * C_MOL + c4);
        a0 += bf2f(v.x); a1 += bf2f(v.y); a2 += bf2f(v.z); a3 += bf2f(v.w);
    }
    ushort4v r;
    r.x = f2bf(a0 * (1.f / 9.f)); r.y = f2bf(a1 * (1.f / 9.f));
    r.z = f2bf(a2 * (1.f / 9.f)); r.w = f2bf(a3 * (1.f / 9.f));
    *(ushort4v*)(out + (size_t)n * C_MOL + c4) = r;
}

// ---------------- fused transpose + fold (both modalities) ----------------

__device__ __forceinline__ void tf_tile(const float* __restrict__ W, u16* __restrict__ Wt,
                                        const float* __restrict__ asrc,
                                        const float* __restrict__ adst, float* __restrict__ wsrc,
                                        float* __restrict__ wdst, int CIN, int COUT,
                                        size_t headStride, int ldn, int h, int n0, int k0) {
    __shared__ float t[32][33];
    __shared__ float rs[8][33], rd[8][33];
    const int tx = threadIdx.x & 31, ty = threadIdx.x >> 5;
#pragma unroll
    for (int q = 0; q < 4; ++q)
        t[ty + q * 8][tx] = W[(size_t)(k0 + ty + q * 8) * (H_HEADS * COUT) + h * COUT + n0 + tx];
    __syncthreads();
#pragma unroll
    for (int q = 0; q < 4; ++q)
        Wt[(size_t)h * headStride + (size_t)(n0 + ty + q * 8) * ldn + k0 + tx] =
            f2bf(t[tx][ty + q * 8]);
    float ps = 0.f, pd = 0.f;
    const float* as = asrc + h * COUT + n0;
    const float* ad = adst + h * COUT + n0;
#pragma unroll
    for (int q = 0; q < 4; ++q) {
        const float w = t[tx][ty + q * 8];
        ps += w * as[ty + q * 8];
        pd += w * ad[ty + q * 8];
    }
    rs[ty][tx] = ps;
    rd[ty][tx] = pd;
    __syncthreads();
    if (ty == 0) {
        float s = 0.f, d = 0.f;
#pragma unroll
        for (int j = 0; j < 8; ++j) { s += rs[j][tx]; d += rd[j][tx]; }
        atomicAdd(&wsrc[h * CIN + k0 + tx], s);
        atomicAdd(&wdst[h * CIN + k0 + tx], d);
    }
}

constexpr int TF_MOL_BLOCKS = (C_MOL / 32) * (C_MOL / 32) * H_HEADS;     // 768
constexpr int TF_PROT_BLOCKS = (C_PROT / 32) * (C_PROT / 32) * H_HEADS;  // 4800

__global__ __launch_bounds__(256) void transfold_both(
    const float* __restrict__ WM, u16* __restrict__ WtM, const float* __restrict__ asrcM,
    const float* __restrict__ adstM, float* __restrict__ wsrcM, float* __restrict__ wdstM,
    const float* __restrict__ WP, u16* __restrict__ WtP, const float* __restrict__ asrcP,
    const float* __restrict__ adstP, float* __restrict__ wsrcP, float* __restrict__ wdstP) {
    const int bid = blockIdx.x;
    if (bid < TF_MOL_BLOCKS) {
        constexpr int G = C_MOL / 32;
        const int h = bid / (G * G), r = bid % (G * G);
        tf_tile(WM, WtM, asrcM, adstM, wsrcM, wdstM, C_MOL, C_MOL, (size_t)C_MOL, 3 * C_MOL, h,
                (r % G) * 32, (r / G) * 32);
    } else {
        constexpr int G = C_PROT / 32;
        const int b2 = bid - TF_MOL_BLOCKS;
        const int h = b2 / (G * G), r = b2 % (G * G);
        tf_tile(WP, WtP, asrcP, adstP, wsrcP, wdstP, C_PROT, C_PROT, (size_t)C_PROT, 3 * C_PROT, h,
                (r % G) * 32, (r / G) * 32);
    }
}

// ---------------- attention logits (layer 0, both modalities) ----------------

template <int C>
__device__ __forceinline__ void logits_node(const u16* __restrict__ x,
                                            const float* __restrict__ wsrc,
                                            const float* __restrict__ wdst,
                                            float* __restrict__ als, float* __restrict__ ald,
                                            int n) {
    constexpr int PER = C / 64;
    const int lane = threadIdx.x;
    const u16* xr = x + (size_t)n * C + lane * PER;
    float xv[PER];
#pragma unroll
    for (int i = 0; i < PER; i += 4) {
        const ushort4v v = *(const ushort4v*)(xr + i);
        xv[i] = bf2f(v.x); xv[i + 1] = bf2f(v.y); xv[i + 2] = bf2f(v.z); xv[i + 3] = bf2f(v.w);
    }
    for (int h = 0; h < H_HEADS; ++h) {
        const float* ws = wsrc + h * C + lane * PER;
        const float* wd = wdst + h * C + lane * PER;
        float ss = 0.f, sd = 0.f;
#pragma unroll
        for (int i = 0; i < PER; i += 4) {
            const float4 a = *(const float4*)(ws + i);
            const float4 b = *(const float4*)(wd + i);
            ss += xv[i] * a.x + xv[i + 1] * a.y + xv[i + 2] * a.z + xv[i + 3] * a.w;
            sd += xv[i] * b.x + xv[i + 1] * b.y + xv[i + 2] * b.z + xv[i + 3] * b.w;
        }
        for (int o = 32; o; o >>= 1) { ss += __shfl_down(ss, o); sd += __shfl_down(sd, o); }
        if (lane == 0) { als[n * H_HEADS + h] = ss; ald[n * H_HEADS + h] = sd; }
    }
}

__global__ __launch_bounds__(64) void logits_both(
    const u16* __restrict__ xM, const float* __restrict__ wsM, const float* __restrict__ wdM,
    float* __restrict__ alsM, float* __restrict__ aldM, const u16* __restrict__ xP,
    const float* __restrict__ wsP, const float* __restrict__ wdP, float* __restrict__ alsP,
    float* __restrict__ aldP) {
    const int b = blockIdx.x;
    if (b < N_MOL)
        logits_node<C_MOL>(xM, wsM, wdM, alsM, aldM, b);
    else
        logits_node<C_PROT>(xP, wsP, wdP, alsP, aldP, b - N_MOL);
}

// ---------------- merged aggregates (parallel-gather m/z, R14-proven) ----------------

__device__ __forceinline__ void agg_mol_part(const u16* __restrict__ x,
                                             const float* __restrict__ als,
                                             const float* __restrict__ ald,
                                             const int* __restrict__ indptr,
                                             const int* __restrict__ srcl, u16* __restrict__ agg,
                                             float* smem) {
    constexpr int MAXD = 128;
    const int wv = threadIdx.x >> 6, lane = threadIdx.x & 63;
    const int n = blockIdx.x * 5 + wv;
    const int beg = indptr[n], end = indptr[n + 1];
    const int deg = end - beg;
    float* atab = smem + wv * (MAXD * 3);
    const float ad0 = ald[n * H_HEADS + 0], ad1 = ald[n * H_HEADS + 1], ad2 = ald[n * H_HEADS + 2];
    const bool fits = deg <= MAXD;
    if (fits) {
        for (int i = lane; i < deg * 3; i += 64) {
            const int e = i / 3, h = i - e * 3;
            float v = als[srcl[beg + e] * H_HEADS + h] + (h == 0 ? ad0 : (h == 1 ? ad1 : ad2));
            atab[i] = v >= 0.f ? v : NEG_SLOPE * v;
        }
    }
    __syncthreads();
    float m = -1e30f, zi = 0.f;
    if (lane < H_HEADS) {
        if (fits) {
            for (int e = 0; e < deg; ++e) m = fmaxf(m, atab[e * 3 + lane]);
            float z = 0.f;
            for (int e = 0; e < deg; ++e) z += __expf(atab[e * 3 + lane] - m);
            zi = 1.f / (z + 1e-16f);
        } else {
            const float ad = lane == 0 ? ad0 : (lane == 1 ? ad1 : ad2);
            for (int e = beg; e < end; ++e) {
                float v = als[srcl[e] * H_HEADS + lane] + ad;
                v = v >= 0.f ? v : NEG_SLOPE * v;
                m = fmaxf(m, v);
            }
            float z = 0.f;
            for (int e = beg; e < end; ++e) {
                float v = als[srcl[e] * H_HEADS + lane] + ad;
                v = v >= 0.f ? v : NEG_SLOPE * v;
                z += __expf(v - m);
            }
            zi = 1.f / (z + 1e-16f);
        }
    }
    const float m0 = __shfl(m, 0), m1 = __shfl(m, 1), m2 = __shfl(m, 2);
    const float z0 = __shfl(zi, 0), z1 = __shfl(zi, 1), z2 = __shfl(zi, 2);
    if (fits) {
        for (int i = lane; i < deg * 3; i += 64) {
            const int h = i - (i / 3) * 3;
            atab[i] = __expf(atab[i] - (h == 0 ? m0 : (h == 1 ? m1 : m2))) *
                      (h == 0 ? z0 : (h == 1 ? z1 : z2));
        }
    }
    __syncthreads();
    float acc[H_HEADS][8];
#pragma unroll
    for (int h = 0; h < H_HEADS; ++h)
#pragma unroll
        for (int j = 0; j < 8; ++j) acc[h][j] = 0.f;
    for (int e = 0; e < deg; ++e) {
        const int s = srcl[beg + e];
        float a0, a1, a2;
        if (fits) {
            a0 = atab[e * 3 + 0]; a1 = atab[e * 3 + 1]; a2 = atab[e * 3 + 2];
        } else {
            float v0 = als[s * H_HEADS + 0] + ad0; v0 = v0 >= 0.f ? v0 : NEG_SLOPE * v0;
            float v1 = als[s * H_HEADS + 1] + ad1; v1 = v1 >= 0.f ? v1 : NEG_SLOPE * v1;
            float v2 = als[s * H_HEADS + 2] + ad2; v2 = v2 >= 0.f ? v2 : NEG_SLOPE * v2;
            a0 = __expf(v0 - m0) * z0; a1 = __expf(v1 - m1) * z1; a2 = __expf(v2 - m2) * z2;
        }
        const short8v row = *(const short8v*)(x + (size_t)s * C_MOL + lane * 8);
#pragma unroll
        for (int j = 0; j < 8; ++j) {
            const float f = bf2f((u16)row[j]);
            acc[0][j] += a0 * f; acc[1][j] += a1 * f; acc[2][j] += a2 * f;
        }
    }
    u16* o = agg + (size_t)n * (3 * C_MOL) + lane * 8;
#pragma unroll
    for (int h = 0; h < H_HEADS; ++h) {
        short8v r;
#pragma unroll
        for (int j = 0; j < 8; ++j) r[j] = (short)f2bf(acc[h][j]);
        *(short8v*)(o + h * C_MOL) = r;
    }
}

__device__ __forceinline__ void agg_prot_part(const u16* __restrict__ x,
                                              const float* __restrict__ als,
                                              const float* __restrict__ ald,
                                              const int* __restrict__ indptr,
                                              const int* __restrict__ srcl, u16* __restrict__ agg,
                                              float* smem, int n) {
    constexpr int MAXD = 500;
    const int tid = threadIdx.x;
    const int beg = indptr[n], end = indptr[n + 1];
    const int deg = end - beg;
    float* mz = smem;
    float* atab = smem + 6;
    const float ad0 = ald[n * H_HEADS + 0], ad1 = ald[n * H_HEADS + 1], ad2 = ald[n * H_HEADS + 2];
    const bool fits = deg <= MAXD;
    if (fits) {
        for (int i = tid; i < deg * 3; i += 320) {
            const int e = i / 3, h = i - e * 3;
            float v = als[srcl[beg + e] * H_HEADS + h] + (h == 0 ? ad0 : (h == 1 ? ad1 : ad2));
            atab[i] = v >= 0.f ? v : NEG_SLOPE * v;
        }
    }
    __syncthreads();
    if (tid < H_HEADS) {
        float m = -1e30f, z = 0.f;
        if (fits) {
            for (int e = 0; e < deg; ++e) m = fmaxf(m, atab[e * 3 + tid]);
            for (int e = 0; e < deg; ++e) z += __expf(atab[e * 3 + tid] - m);
        } else {
            const float ad = tid == 0 ? ad0 : (tid == 1 ? ad1 : ad2);
            for (int e = beg; e < end; ++e) {
                float v = als[srcl[e] * H_HEADS + tid] + ad;
                v = v >= 0.f ? v : NEG_SLOPE * v;
                m = fmaxf(m, v);
            }
            for (int e = beg; e < end; ++e) {
                float v = als[srcl[e] * H_HEADS + tid] + ad;
                v = v >= 0.f ? v : NEG_SLOPE * v;
                z += __expf(v - m);
            }
        }
        mz[tid] = m;
        mz[3 + tid] = 1.f / (z + 1e-16f);
    }
    __syncthreads();
    const float m0 = mz[0], m1 = mz[1], m2 = mz[2];
    const float z0 = mz[3], z1 = mz[4], z2 = mz[5];
    if (fits) {
        for (int i = tid; i < deg * 3; i += 320) {
            const int h = i - (i / 3) * 3;
            atab[i] = __expf(atab[i] - (h == 0 ? m0 : (h == 1 ? m1 : m2))) *
                      (h == 0 ? z0 : (h == 1 ? z1 : z2));
        }
    }
    __syncthreads();
    float acc[H_HEADS][4];
#pragma unroll
    for (int h = 0; h < H_HEADS; ++h)
#pragma unroll
        for (int j = 0; j < 4; ++j) acc[h][j] = 0.f;
    for (int e = 0; e < deg; ++e) {
        const int s = srcl[beg + e];
        float a0, a1, a2;
        if (fits) {
            a0 = atab[e * 3 + 0]; a1 = atab[e * 3 + 1]; a2 = atab[e * 3 + 2];
        } else {
            float v0 = als[s * H_HEADS + 0] + ad0; v0 = v0 >= 0.f ? v0 : NEG_SLOPE * v0;
            float v1 = als[s * H_HEADS + 1] + ad1; v1 = v1 >= 0.f ? v1 : NEG_SLOPE * v1;
            float v2 = als[s * H_HEADS + 2] + ad2; v2 = v2 >= 0.f ? v2 : NEG_SLOPE * v2;
            a0 = __expf(v0 - m0) * z0; a1 = __expf(v1 - m1) * z1; a2 = __expf(v2 - m2) * z2;
        }
        const ushort4v v = *(const ushort4v*)(x + (size_t)s * C_PROT + tid * 4);
        const float f0 = bf2f(v.x), f1 = bf2f(v.y), f2 = bf2f(v.z), f3 = bf2f(v.w);
        acc[0][0] += a0 * f0; acc[0][1] += a0 * f1; acc[0][2] += a0 * f2; acc[0][3] += a0 * f3;
        acc[1][0] += a1 * f0; acc[1][1] += a1 * f1; acc[1][2] += a1 * f2; acc[1][3] += a1 * f3;
        acc[2][0] += a2 * f0; acc[2][1] += a2 * f1; acc[2][2] += a2 * f2; acc[2][3] += a2 * f3;
    }
    u16* o = agg + (size_t)n * (3 * C_PROT) + tid * 4;
#pragma unroll
    for (int h = 0; h < H_HEADS; ++h) {
        ushort4v r;
        r.x = f2bf(acc[h][0]); r.y = f2bf(acc[h][1]); r.z = f2bf(acc[h][2]); r.w = f2bf(acc[h][3]);
        *(ushort4v*)(o + h * C_PROT) = r;
    }
}

__global__ __launch_bounds__(320) void agg_both(
    const u16* __restrict__ xM, const float* __restrict__ alsM, const float* __restrict__ aldM,
    const int* __restrict__ iptrM, const int* __restrict__ srclM, u16* __restrict__ aggM,
    const u16* __restrict__ xP, const float* __restrict__ alsP, const float* __restrict__ aldP,
    const int* __restrict__ iptrP, const int* __restrict__ srclP, u16* __restrict__ aggP,
    int molBlocks) {
    __shared__ float smem[1920];
    if ((int)blockIdx.x < molBlocks)
        agg_mol_part(xM, alsM, aldM, iptrM, srclM, aggM, smem);
    else
        agg_prot_part(xP, alsP, aldP, iptrP, srclP, aggP, smem, blockIdx.x - molBlocks);
}

// ---------------- GEMM: 128x128 tile, BK=64, DBUF 64KB + counted vmcnt (R15 proven) ----------------

__global__ __launch_bounds__(256) void gemm128p(
    const u16* __restrict__ A0, const u16* __restrict__ B0, u16* __restrict__ C0,
    int N0, int K0, int nx0, int M0, int g0,
    const u16* __restrict__ A1, const u16* __restrict__ B1, u16* __restrict__ C1,
    int N1, int K1, int nx1, int M1) {
    __shared__ u16 lds[32768];
    const int tid = threadIdx.x;
    const int w = tid >> 6, l = tid & 63;
    const int wr = w >> 1, wc = w & 1;

    const int bid = blockIdx.x;
    const u16 *A, *Bt;
    u16* Cout;
    int N, K, nxch, Mreal, base, sz;
    if (bid < g0) { base = 0; sz = g0; A = A0; Bt = B0; Cout = C0; N = N0; K = K0; nxch = nx0; Mreal = M0; }
    else { base = g0; sz = gridDim.x - g0; A = A1; Bt = B1; Cout = C1; N = N1; K = K1; nxch = nx1; Mreal = M1; }
    const int j = bid - base;
    const int q = sz >> 3, r = sz & 7;
    const int xcd = j & 7, idx = j >> 3;
    const int wg = (xcd < r ? xcd * (q + 1) : r * (q + 1) + (xcd - r) * q) + idx;
    const int nx = wg % nxch, my = wg / nxch;
    const size_t bm = (size_t)my * 128, bn = (size_t)nx * 128;

    const f32x4 zf = {0.f, 0.f, 0.f, 0.f};
    f32x4 acc[4][4];
#pragma unroll
    for (int i = 0; i < 4; ++i)
#pragma unroll
        for (int jj = 0; jj < 4; ++jj) acc[i][jj] = zf;

    const int srow = w * 32 + (l >> 3);
    const int sseg = (l & 7) ^ (l >> 3);
    const u16* Ab = A + (bm + srow) * (size_t)K + sseg * 8;
    const u16* Bb = Bt + (bn + srow) * (size_t)K + sseg * 8;

    auto stage = [&](int buf, int k0) {
        u16* La = lds + buf * 16384;
#pragma unroll
        for (int qq = 0; qq < 4; ++qq)
            g2l16(Ab + k0 + (size_t)qq * 8 * K, La + (w * 4 + qq) * 512);
#pragma unroll
        for (int qq = 0; qq < 4; ++qq)
            g2l16(Bb + k0 + (size_t)qq * 8 * K, La + 8192 + (w * 4 + qq) * 512);
    };

    const int nt = K >> 6;
    stage(0, 0);
    for (int t = 0; t < nt; ++t) {
        const int cur = t & 1;
        if (t + 1 < nt) {
            stage(cur ^ 1, (t + 1) << 6);
            asm volatile("s_waitcnt vmcnt(8)" ::: "memory");
        } else {
            asm volatile("s_waitcnt vmcnt(0)" ::: "memory");
        }
        __builtin_amdgcn_s_barrier();
        __builtin_amdgcn_sched_barrier(0);
        const u16* Lb = lds + cur * 16384;
#pragma unroll
        for (int kk = 0; kk < 2; ++kk) {
            const int sg = ((kk * 4 + (l >> 4)) ^ (l & 7)) * 8;
            short8v af[4], bf8[4];
#pragma unroll
            for (int fm = 0; fm < 4; ++fm) {
                const int row = wr * 64 + fm * 16 + (l & 15);
                af[fm] = *(const short8v*)&Lb[row * 64 + sg];
            }
#pragma unroll
            for (int fn = 0; fn < 4; ++fn) {
                const int row = wc * 64 + fn * 16 + (l & 15);
                bf8[fn] = *(const short8v*)&Lb[8192 + row * 64 + sg];
            }
#pragma unroll
            for (int fm = 0; fm < 4; ++fm)
#pragma unroll
                for (int fn = 0; fn < 4; ++fn)
                    acc[fm][fn] = __builtin_amdgcn_mfma_f32_16x16x32_bf16(af[fm], bf8[fn],
                                                                          acc[fm][fn], 0, 0, 0);
        }
        __builtin_amdgcn_sched_barrier(0);
        __builtin_amdgcn_s_barrier();
    }

#pragma unroll
    for (int half = 0; half < 2; ++half) {
        if (wr == half) {
#pragma unroll
            for (int fm = 0; fm < 4; ++fm)
#pragma unroll
                for (int fn = 0; fn < 4; ++fn) {
                    const int col = wc * 64 + fn * 16 + (l & 15);
#pragma unroll
                    for (int rr = 0; rr < 4; ++rr)
                        lds[(fm * 16 + (l >> 4) * 4 + rr) * 136 + col] = f2bf(acc[fm][fn][rr]);
                }
        }
        __syncthreads();
        const int lrow = tid >> 2, lseg = tid & 3;
        const size_t grow = bm + half * 64 + lrow;
        if (grow < (size_t)Mreal) {
            u16* Crow = Cout + grow * (size_t)N + bn + lseg * 32;
            const u16* Lr = lds + lrow * 136 + lseg * 32;
#pragma unroll
            for (int ii = 0; ii < 4; ++ii)
                *(float4*)(Crow + ii * 8) = *(const float4*)(Lr + ii * 8);
        }
        __syncthreads();
    }
}

// ---------------- in-place LN, vectorized + next-layer logits ----------------

template <int C, int LOGITS>
__global__ __launch_bounds__(C / 4) void ln_kernel(u16* __restrict__ x,
                                                   const float* __restrict__ bias,
                                                   const float* __restrict__ g,
                                                   const float* __restrict__ b,
                                                   const float* __restrict__ wsrc_n,
                                                   const float* __restrict__ wdst_n,
                                                   float* __restrict__ als,
                                                   float* __restrict__ ald) {
    constexpr int NT = C / 4;
    constexpr int NW = NT / 64;
    const int n = blockIdx.x, tid = threadIdx.x;
    u16* xr = x + (size_t)n * C + tid * 4;
    constexpr float invH = 1.f / (float)H_HEADS;
    const ushort4v xv = *(const ushort4v*)xr;
    const float4 bi = *(const float4*)(bias + tid * 4);
    const float v0 = bf2f(xv.x) * invH + bi.x;
    const float v1 = bf2f(xv.y) * invH + bi.y;
    const float v2 = bf2f(xv.z) * invH + bi.z;
    const float v3 = bf2f(xv.w) * invH + bi.w;
    float s1 = v0 + v1 + v2 + v3;
    float s2 = v0 * v0 + v1 * v1 + v2 * v2 + v3 * v3;
    __shared__ float red[2][NW];
    __shared__ float red2[NW][6];
    for (int o = 32; o; o >>= 1) { s1 += __shfl_down(s1, o); s2 += __shfl_down(s2, o); }
    if ((tid & 63) == 0) { red[0][tid >> 6] = s1; red[1][tid >> 6] = s2; }
    __syncthreads();
    float t1 = 0.f, t2 = 0.f;
#pragma unroll
    for (int i = 0; i < NW; ++i) { t1 += red[0][i]; t2 += red[1][i]; }
    const float mu = t1 / C;
    const float var = t2 / C - mu * mu;
    const float rstd = rsqrtf(var + LN_EPS);
    const float4 gg = *(const float4*)(g + tid * 4);
    const float4 bb = *(const float4*)(b + tid * 4);
    ushort4v ov;
    ov.x = f2bf((v0 - mu) * rstd * gg.x + bb.x);
    ov.y = f2bf((v1 - mu) * rstd * gg.y + bb.y);
    ov.z = f2bf((v2 - mu) * rstd * gg.z + bb.z);
    ov.w = f2bf((v3 - mu) * rstd * gg.w + bb.w);
    *(ushort4v*)xr = ov;
    if (LOGITS) {
        const float q0 = bf2f(ov.x), q1 = bf2f(ov.y), q2 = bf2f(ov.z), q3 = bf2f(ov.w);
        float ps[3], pd[3];
#pragma unroll
        for (int h = 0; h < 3; ++h) {
            const float4 a = *(const float4*)(wsrc_n + h * C + tid * 4);
            const float4 d = *(const float4*)(wdst_n + h * C + tid * 4);
            ps[h] = q0 * a.x + q1 * a.y + q2 * a.z + q3 * a.w;
            pd[h] = q0 * d.x + q1 * d.y + q2 * d.z + q3 * d.w;
        }
        for (int o = 32; o; o >>= 1) {
#pragma unroll
            for (int h = 0; h < 3; ++h) {
                ps[h] += __shfl_down(ps[h], o);
                pd[h] += __shfl_down(pd[h], o);
            }
        }
        if ((tid & 63) == 0) {
            const int wv = tid >> 6;
#pragma unroll
            for (int h = 0; h < 3; ++h) { red2[wv][h] = ps[h]; red2[wv][3 + h] = pd[h]; }
        }
        __syncthreads();
        if (tid == 0) {
#pragma unroll
            for (int h = 0; h < 3; ++h) {
                float as = 0.f, ad = 0.f;
#pragma unroll
                for (int i = 0; i < NW; ++i) { as += red2[i][h]; ad += red2[i][3 + h]; }
                als[n * H_HEADS + h] = as;
                ald[n * H_HEADS + h] = ad;
            }
        }
    }
}

// ---------------- merged mol+prot segmented mean-pool ----------------

__global__ __launch_bounds__(320) void pool_both(const u16* __restrict__ xM,
                                                 const int* __restrict__ goffM,
                                                 float* __restrict__ outM,
                                                 const u16* __restrict__ xP,
                                                 const int* __restrict__ goffP,
                                                 float* __restrict__ outP, int layer,
                                                 int molBlocks) {
    const int b = blockIdx.x;
    const int tid = threadIdx.x;
    if (b < molBlocks) {
        if (tid >= C_MOL / 4) return;
        const int g = b >> 3, seg = b & 7;
        const int beg = goffM[g], end = goffM[g + 1];
        const int len = end - beg;
        const int s0 = beg + (len * seg) / 8;
        const int s1 = beg + (len * (seg + 1)) / 8;
        if (s0 >= s1) return;
        const float inv = 1.f / fmaxf((float)len, 1.f);
        float a0 = 0.f, a1 = 0.f, a2 = 0.f, a3 = 0.f;
        for (int n = s0; n < s1; ++n) {
            const ushort4v v = *(const ushort4v*)(xM + (size_t)n * C_MOL + tid * 4);
            a0 += bf2f(v.x); a1 += bf2f(v.y); a2 += bf2f(v.z); a3 += bf2f(v.w);
        }
        float* o = outM + ((size_t)g * (LAYERS + 1) + layer) * C_MOL + tid * 4;
        atomicAdd(o + 0, a0 * inv);
        atomicAdd(o + 1, a1 * inv);
        atomicAdd(o + 2, a2 * inv);
        atomicAdd(o + 3, a3 * inv);
    } else {
        const int bb = b - molBlocks;
        const int g = bb >> 6, seg = bb & 63;
        const int beg = goffP[g], end = goffP[g + 1];
        const int len = end - beg;
        const int s0 = beg + (len * seg) / 64;
        const int s1 = beg + (len * (seg + 1)) / 64;
        if (s0 >= s1) return;
        const float inv = 1.f / fmaxf((float)len, 1.f);
        float a0 = 0.f, a1 = 0.f, a2 = 0.f, a3 = 0.f;
        for (int n = s0; n < s1; ++n) {
            const ushort4v v = *(const ushort4v*)(xP + (size_t)n * C_PROT + tid * 4);
            a0 += bf2f(v.x); a1 += bf2f(v.y); a2 += bf2f(v.z); a3 += bf2f(v.w);
        }
        float* o = outP + ((size_t)g * (LAYERS + 1) + layer) * C_PROT + tid * 4;
        atomicAdd(o + 0, a0 * inv);
        atomicAdd(o + 1, a1 * inv);
        atomicAdd(o + 2, a2 * inv);
        atomicAdd(o + 3, a3 * inv);
    }
}

// ---------------- launch ----------------

extern "C" void kernel_launch(void* const* d_in, const int* in_sizes, int n_in, void* d_out,
                              int out_size, void* d_ws, size_t ws_size, hipStream_t stream) {
    const int* drug_x      = (const int*)d_in[0];
    const int* mol_ei      = (const int*)d_in[1];
    const int* mol_batch   = (const int*)d_in[2];
    const float* prot_in   = (const float*)d_in[3];
    const int* prot_ei     = (const int*)d_in[4];
    const int* prot_batch  = (const int*)d_in[5];
    const float* emb       = (const float*)d_in[6];
    const float* mol_W     = (const float*)d_in[7];
    const float* mol_asrc  = (const float*)d_in[8];
    const float* mol_adst  = (const float*)d_in[9];
    const float* mol_bias  = (const float*)d_in[10];
    const float* mol_lng   = (const float*)d_in[11];
    const float* mol_lnb   = (const float*)d_in[12];
    const float* prot_W    = (const float*)d_in[13];
    const float* prot_asrc = (const float*)d_in[14];
    const float* prot_adst = (const float*)d_in[15];
    const float* prot_bias = (const float*)d_in[16];
    const float* prot_lng  = (const float*)d_in[17];
    const float* prot_lnb  = (const float*)d_in[18];

    if (ws_size < (size_t)262000000) return;

    char* base = (char*)d_ws;
    size_t off = 0;
    auto alloc = [&](size_t bytes) -> void* {
        void* r = base + off;
        off = (off + bytes + 255) & ~(size_t)255;
        return r;
    };
    u16* x_mol  = (u16*)alloc((size_t)N_MOL * C_MOL * 2);
    u16* x_prot = (u16*)alloc((size_t)N_PROT * C_PROT * 2);
    u16* aggM   = (u16*)alloc((size_t)3 * MPAD_MOL * C_MOL * 2);
    u16* WtM    = (u16*)alloc((size_t)H_HEADS * C_MOL * C_MOL * 2);
    u16* WtP    = (u16*)alloc((size_t)H_HEADS * C_PROT * C_PROT * 2);
    u16* aggP   = (u16*)alloc((size_t)3 * MPAD_PROT * C_PROT * 2);
    float* wsrcM = (float*)alloc((size_t)LAYERS * H_HEADS * C_MOL * 4);
    float* wdstM = (float*)alloc((size_t)LAYERS * H_HEADS * C_MOL * 4);
    float* wsrcP = (float*)alloc((size_t)LAYERS * H_HEADS * C_PROT * 4);
    float* wdstP = (float*)alloc((size_t)LAYERS * H_HEADS * C_PROT * 4);
    float* alsM = (float*)alloc((size_t)N_MOL * H_HEADS * 4);
    float* aldM = (float*)alloc((size_t)N_MOL * H_HEADS * 4);
    float* alsP = (float*)alloc((size_t)N_PROT * H_HEADS * 4);
    float* aldP = (float*)alloc((size_t)N_PROT * H_HEADS * 4);
    int* mol_indptr  = (int*)alloc((N_MOL + 1) * 4);
    int* mol_pos     = (int*)alloc(N_MOL * 4);
    int* mol_srcl    = (int*)alloc((E_MOL + N_MOL) * 4);
    int* prot_indptr = (int*)alloc((N_PROT + 1) * 4);
    int* prot_pos    = (int*)alloc(N_PROT * 4);
    int* prot_srcl   = (int*)alloc((E_PROT + N_PROT) * 4);
    int* cntM        = (int*)alloc(N_MOL * 4);
    int* cntP        = (int*)alloc(N_PROT * 4);
    int* mol_goff    = (int*)alloc((G_MOL + 1) * 4);
    int* prot_goff   = (int*)alloc((G_PROT + 1) * 4);
    int* gcntM       = (int*)alloc(G_MOL * 4);
    int* gcntP       = (int*)alloc(G_PROT * 4);

    u16* emb_bf = aggM;  // alias: aggM dead until first agg_both

    float* out_mol  = (float*)d_out;
    float* out_prot = (float*)d_out + (size_t)G_MOL * (LAYERS + 1) * C_MOL;

    {
        const int total = N_MOL + N_PROT + G_MOL + G_PROT + FOLD_F32 + out_size;
        init_all<<<(total + 255) / 256, 256, 0, stream>>>(cntM, cntP, gcntM, gcntP, wsrcM,
                                                          (float*)d_out, out_size);
    }

    hist_both<<<(E_MOL + E_PROT + 255) / 256, 256, 0, stream>>>(mol_ei + E_MOL, cntM,
                                                                prot_ei + E_PROT, cntP);
    scan2<<<2, 1024, 0, stream>>>(cntM, mol_indptr, N_MOL, cntP, prot_indptr, N_PROT);
    copy_pos_both<<<(N_MOL + N_PROT + 255) / 256, 256, 0, stream>>>(mol_indptr, mol_pos,
                                                                    prot_indptr, prot_pos);
    fill_self_both<<<(N_MOL + N_PROT + 255) / 256, 256, 0, stream>>>(mol_pos, mol_srcl, prot_pos,
                                                                     prot_srcl);
    fill_edge_both<<<(E_MOL + E_PROT + 255) / 256, 256, 0, stream>>>(mol_ei, mol_pos, mol_srcl,
                                                                     prot_ei, prot_pos, prot_srcl);
    hist_batch_both<<<(N_MOL + N_PROT + 255) / 256, 256, 0, stream>>>(mol_batch, gcntM, prot_batch,
                                                                      gcntP);
    scan2<<<2, 1024, 0, stream>>>(gcntM, mol_goff, G_MOL, gcntP, prot_goff, G_PROT);

    transfold_both<<<TF_MOL_BLOCKS + TF_PROT_BLOCKS, 256, 0, stream>>>(
        mol_W, WtM, mol_asrc, mol_adst, wsrcM, wdstM,
        prot_W, WtP, prot_asrc, prot_adst, wsrcP, wdstP);

    f32bf_both<<<(VOCAB * C_MOL + N_PROT * C_PROT + 255) / 256, 256, 0, stream>>>(
        emb, emb_bf, VOCAB * C_MOL, prot_in, x_prot, N_PROT * C_PROT);
    embed_mean_v<<<N_MOL, 128, 0, stream>>>(drug_x, emb_bf, x_mol);
    pool_both<<<G_MOL * 8 + G_PROT * 64, 320, 0, stream>>>(x_mol, mol_goff, out_mol, x_prot,
                                                           prot_goff, out_prot, 0, G_MOL * 8);
    logits_both<<<N_MOL + N_PROT, 64, 0, stream>>>(x_mol, wsrcM, wdstM, alsM, aldM, x_prot, wsrcP,
                                                   wdstP, alsP, aldP);

    const int gMol = (MPAD_MOL / 128) * (C_MOL / 128);    // 1252
    const int gProt = (MPAD_PROT / 128) * (C_PROT / 128); // 630
    const int molAggBlocks = N_MOL / 5;                   // 8000

    for (int l = 0; l < LAYERS; ++l) {
        const int last = (l == LAYERS - 1);
        agg_both<<<molAggBlocks + N_PROT, 320, 0, stream>>>(
            x_mol, alsM, aldM, mol_indptr, mol_srcl, aggM,
            x_prot, alsP, aldP, prot_indptr, prot_srcl, aggP, molAggBlocks);
        gemm128p<<<gProt + gMol, 256, 0, stream>>>(
            aggP, WtP, x_prot, C_PROT, 3 * C_PROT, C_PROT / 128, N_PROT, gProt,
            aggM, WtM, x_mol, C_MOL, 3 * C_MOL, C_MOL / 128, N_MOL);
        if (!last) {
            transfold_both<<<TF_MOL_BLOCKS + TF_PROT_BLOCKS, 256, 0, stream>>>(
                mol_W + (size_t)(l + 1) * C_MOL * (H_HEADS * C_MOL), WtM,
                mol_asrc + (size_t)(l + 1) * H_HEADS * C_MOL,
                mol_adst + (size_t)(l + 1) * H_HEADS * C_MOL,
                wsrcM + (size_t)(l + 1) * H_HEADS * C_MOL,
                wdstM + (size_t)(l + 1) * H_HEADS * C_MOL,
                prot_W + (size_t)(l + 1) * C_PROT * (H_HEADS * C_PROT), WtP,
                prot_asrc + (size_t)(l + 1) * H_HEADS * C_PROT,
                prot_adst + (size_t)(l + 1) * H_HEADS * C_PROT,
                wsrcP + (size_t)(l + 1) * H_HEADS * C_PROT,
                wdstP + (size_t)(l + 1) * H_HEADS * C_PROT);
            ln_kernel<C_MOL, 1><<<N_MOL, C_MOL / 4, 0, stream>>>(
                x_mol, mol_bias + (size_t)l * C_MOL, mol_lng + (size_t)l * C_MOL,
                mol_lnb + (size_t)l * C_MOL, wsrcM + (size_t)(l + 1) * H_HEADS * C_MOL,
                wdstM + (size_t)(l + 1) * H_HEADS * C_MOL, alsM, aldM);
            ln_kernel<C_PROT, 1><<<N_PROT, C_PROT / 4, 0, stream>>>(
                x_prot, prot_bias + (size_t)l * C_PROT, prot_lng + (size_t)l * C_PROT,
                prot_lnb + (size_t)l * C_PROT, wsrcP + (size_t)(l + 1) * H_HEADS * C_PROT,
                wdstP + (size_t)(l + 1) * H_HEADS * C_PROT, alsP, aldP);
        } else {
            ln_kernel<C_MOL, 0><<<N_MOL, C_MOL / 4, 0, stream>>>(
                x_mol, mol_bias + (size_t)l * C_MOL, mol_lng + (size_t)l * C_MOL,
                mol_lnb + (size_t)l * C_MOL, nullptr, nullptr, nullptr, nullptr);
            ln_kernel<C_PROT, 0><<<N_PROT, C_PROT / 4, 0, stream>>>(
                x_prot, prot_bias + (size_t)l * C_PROT, prot_lng + (size_t)l * C_PROT,
                prot_lnb + (size_t)l * C_PROT, nullptr, nullptr, nullptr, nullptr);
        }
        pool_both<<<G_MOL * 8 + G_PROT * 64, 320, 0, stream>>>(x_mol, mol_goff, out_mol, x_prot,
                                                               prot_goff, out_prot, l + 1,
                                                               G_MOL * 8);
    }
}